// Round 4
// baseline (3325.445 us; speedup 1.0000x reference)
//
#include <hip/hip_runtime.h>
#include <cstdint>
#include <cstddef>

#define LK(x) ((x) > 0.f ? (x) : 0.01f * (x))

constexpr int B_ = 256;
constexpr int N_ = 256;
constexpr int BN = B_ * N_;
constexpr int CHUNK_B = 64;                 // batches per UV chunk
constexpr int CHUNK_ROWS = CHUNK_B * N_;    // 16384 rows

// ---------------- KNN: one block per batch, one thread per point ----------------
__global__ void knn_kernel(const float* __restrict__ feat, int F, int* __restrict__ idxout) {
  __shared__ float px[N_], py[N_], pz[N_];
  int b = blockIdx.x, t = threadIdx.x;
  const float* row = feat + ((size_t)b * N_ + t) * F;
  px[t] = row[0]; py[t] = row[1]; pz[t] = row[2];
  __syncthreads();
  float x = px[t], y = py[t], z = pz[t];
  float bd0 = INFINITY, bd1 = INFINITY, bd2 = INFINITY, bd3 = INFINITY;
  int bi0 = 0, bi1 = 0, bi2 = 0, bi3 = 0;
  for (int j = 0; j < N_; ++j) {
    #pragma clang fp contract(off)
    float dx = x - px[j], dy = y - py[j], dz = z - pz[j];
    float d = (dx * dx + dy * dy) + dz * dz;
    if (j == t) continue;                 // self excluded (eye -> inf)
    if (d < bd3) {                        // strict <  == top_k lower-index tie-break
      if (d < bd2) {
        bd3 = bd2; bi3 = bi2;
        if (d < bd1) {
          bd2 = bd1; bi2 = bi1;
          if (d < bd0) { bd1 = bd0; bi1 = bi0; bd0 = d; bi0 = j; }
          else         { bd1 = d; bi1 = j; }
        } else         { bd2 = d; bi2 = j; }
      } else           { bd3 = d; bi3 = j; }
    }
  }
  int* o = idxout + ((size_t)b * N_ + t) * 4;
  o[0] = bi0; o[1] = bi1; o[2] = bi2; o[3] = bi3;
}

// -------- prep: wcat = [w1_top - w1_bot | w1_bot] (F x 2H1), bcat = [b1 | 0] --------
__global__ void prep_uvw(const float* __restrict__ w1, const float* __restrict__ b1,
                         int F, int H1, float* __restrict__ wcat, float* __restrict__ bcat) {
  int t = blockIdx.x * 256 + threadIdx.x;
  int FH = F * H1;
  if (t < FH) {
    int k = t / H1, c = t - k * H1;
    float top = w1[(size_t)k * H1 + c];
    float bot = w1[(size_t)(F + k) * H1 + c];
    wcat[(size_t)k * 2 * H1 + c]      = top - bot;
    wcat[(size_t)k * 2 * H1 + H1 + c] = bot;
  }
  if (t < H1) { bcat[t] = b1[t]; bcat[H1 + t] = 0.f; }
}

// -------- tiled fp32 GEMM: C (+)= act?(A) @ W (+ bias) --------
// BM x 128 tile, BK=8, 2*BM threads, 8x8 micro-tile (1 B/FMA from LDS).
template<int BM, bool ACT_A, bool ACCUM, bool HAS_BIAS>
__global__ __launch_bounds__(2 * BM) void gemm_t(
    const float* __restrict__ A, const float* __restrict__ W,
    const float* __restrict__ bias, float* __restrict__ C,
    int M, int N, int K) {
  __shared__ float sA[8][BM + 4];
  __shared__ float sB[8][132];
  int tid = threadIdx.x;
  int m0 = blockIdx.y * BM, n0 = blockIdx.x * 128;
  int kA = tid & 7, mA = tid >> 3;         // staging A: mA < BM/4
  int ty = tid >> 4, tx = tid & 15;        // compute: ty < BM/8
  float acc[8][8] = {};
  for (int k0 = 0; k0 < K; k0 += 8) {
    int kg = k0 + kA;
    #pragma unroll
    for (int i = 0; i < 4; ++i) {
      int m = mA + i * (BM / 4);
      float v = 0.f;
      if (kg < K) { v = A[(size_t)(m0 + m) * K + kg]; if (ACT_A) v = LK(v); }
      sA[kA][m] = v;
    }
    {
      int nB = tid & 127;
      #pragma unroll
      for (int kk = tid >> 7; kk < 8; kk += (2 * BM) >> 7) {
        int kgw = k0 + kk, n = n0 + nB;
        float v = 0.f;
        if (kgw < K && n < N) v = W[(size_t)kgw * N + n];
        sB[kk][nB] = v;
      }
    }
    __syncthreads();
    #pragma unroll
    for (int kk = 0; kk < 8; ++kk) {
      float4 a0 = *(const float4*)&sA[kk][ty * 8];
      float4 a1 = *(const float4*)&sA[kk][ty * 8 + 4];
      float4 b0 = *(const float4*)&sB[kk][tx * 8];
      float4 b1 = *(const float4*)&sB[kk][tx * 8 + 4];
      float av[8] = {a0.x,a0.y,a0.z,a0.w,a1.x,a1.y,a1.z,a1.w};
      float bv[8] = {b0.x,b0.y,b0.z,b0.w,b1.x,b1.y,b1.z,b1.w};
      #pragma unroll
      for (int i = 0; i < 8; ++i)
        #pragma unroll
        for (int j = 0; j < 8; ++j)
          acc[i][j] += av[i] * bv[j];
    }
    __syncthreads();
  }
  int n = n0 + tx * 8;
  float bv[8] = {0,0,0,0,0,0,0,0};
  if (HAS_BIAS) {
    #pragma unroll
    for (int j = 0; j < 8; ++j) if (n + j < N) bv[j] = bias[n + j];
  }
  #pragma unroll
  for (int i = 0; i < 8; ++i) {
    size_t m = (size_t)(m0 + ty * 8 + i);
    if (n + 7 < N) {
      float4 o0, o1;
      o0.x = acc[i][0] + bv[0]; o0.y = acc[i][1] + bv[1];
      o0.z = acc[i][2] + bv[2]; o0.w = acc[i][3] + bv[3];
      o1.x = acc[i][4] + bv[4]; o1.y = acc[i][5] + bv[5];
      o1.z = acc[i][6] + bv[6]; o1.w = acc[i][7] + bv[7];
      float4* cp = (float4*)(C + m * N + n);
      if (ACCUM) {
        float4 t0 = cp[0], t1 = cp[1];
        o0.x += t0.x; o0.y += t0.y; o0.z += t0.z; o0.w += t0.w;
        o1.x += t1.x; o1.y += t1.y; o1.z += t1.z; o1.w += t1.w;
      }
      cp[0] = o0; cp[1] = o1;
    } else {
      #pragma unroll
      for (int j = 0; j < 8; ++j) {
        if (n + j < N) {
          float v = acc[i][j] + bv[j];
          size_t off = m * N + n + j;
          if (ACCUM) v += C[off];
          C[off] = v;
        }
      }
    }
  }
}

// -------- nn1 GEMM: 128x128, A = [A0(192) | A1(192)] tile-aligned segments --------
// FIRST: prologue adds x(K=4)@Wx in k-ascending order, bias in epilogue, plain store.
// !FIRST: accumulate (RMW) into C.
template<bool FIRST>
__global__ __launch_bounds__(256) void gemm_nn1(
    const float* __restrict__ A0, const float* __restrict__ A1,
    const float* __restrict__ X, const float* __restrict__ Wx,
    const float* __restrict__ Wab, const float* __restrict__ bias,
    float* __restrict__ C, int M, int N) {   // N = 252
  __shared__ float sA[8][132];
  __shared__ float sB[8][132];
  __shared__ float sX[128][4];
  __shared__ float sWx[4][132];
  int tid = threadIdx.x;
  int m0 = blockIdx.y * 128, n0 = blockIdx.x * 128;
  int kA = tid & 7, mA = tid >> 3;
  int ty = tid >> 4, tx = tid & 15;
  float acc[8][8] = {};
  if (FIRST) {
    if (tid < 128) *(float4*)&sX[tid][0] = *(const float4*)(X + (size_t)(m0 + tid) * 4);
    #pragma unroll
    for (int p = 0; p < 2; ++p) {
      int q = tid + p * 256;            // 0..511
      int k = q >> 7, n = q & 127;
      float v = 0.f;
      if (n0 + n < N) v = Wx[(size_t)k * N + n0 + n];
      sWx[k][n] = v;
    }
    __syncthreads();
    #pragma unroll
    for (int k = 0; k < 4; ++k) {
      float avx[8], bvx[8];
      #pragma unroll
      for (int i = 0; i < 8; ++i) avx[i] = sX[ty * 8 + i][k];
      #pragma unroll
      for (int j = 0; j < 8; ++j) bvx[j] = sWx[k][tx * 8 + j];
      #pragma unroll
      for (int i = 0; i < 8; ++i)
        #pragma unroll
        for (int j = 0; j < 8; ++j)
          acc[i][j] += avx[i] * bvx[j];
    }
  }
  for (int k0 = 0; k0 < 384; k0 += 8) {
    const float* As = (k0 < 192) ? A0 : A1;    // uniform per tile (192 % 8 == 0)
    int kb = ((k0 < 192) ? k0 : k0 - 192) + kA;
    #pragma unroll
    for (int i = 0; i < 4; ++i) {
      int m = mA + i * 32;
      sA[kA][m] = As[(size_t)(m0 + m) * 192 + kb];
    }
    {
      int nB = tid & 127;
      #pragma unroll
      for (int q = 0; q < 4; ++q) {
        int kk = (tid >> 7) + q * 2;
        int n = n0 + nB;
        float v = 0.f;
        if (n < N) v = Wab[(size_t)(k0 + kk) * N + n];
        sB[kk][nB] = v;
      }
    }
    __syncthreads();
    #pragma unroll
    for (int kk = 0; kk < 8; ++kk) {
      float4 a0 = *(const float4*)&sA[kk][ty * 8];
      float4 a1 = *(const float4*)&sA[kk][ty * 8 + 4];
      float4 b0 = *(const float4*)&sB[kk][tx * 8];
      float4 b1 = *(const float4*)&sB[kk][tx * 8 + 4];
      float av[8] = {a0.x,a0.y,a0.z,a0.w,a1.x,a1.y,a1.z,a1.w};
      float bv[8] = {b0.x,b0.y,b0.z,b0.w,b1.x,b1.y,b1.z,b1.w};
      #pragma unroll
      for (int i = 0; i < 8; ++i)
        #pragma unroll
        for (int j = 0; j < 8; ++j)
          acc[i][j] += av[i] * bv[j];
    }
    __syncthreads();
  }
  int n = n0 + tx * 8;
  float bv[8] = {0,0,0,0,0,0,0,0};
  if (FIRST) {
    #pragma unroll
    for (int j = 0; j < 8; ++j) if (n + j < N) bv[j] = bias[n + j];
  }
  #pragma unroll
  for (int i = 0; i < 8; ++i) {
    size_t m = (size_t)(m0 + ty * 8 + i);
    #pragma unroll
    for (int j = 0; j < 8; ++j) {
      if (n + j < N) {
        float v = acc[i][j] + bv[j];
        size_t off = m * N + n + j;
        if (!FIRST) v += C[off];
        C[off] = v;
      }
    }
  }
}

// ---------------- fused edge stage 2 ----------------
// h1[edge] = leaky(U[i] + V[j]) (b1 in U); out[i] = sum_k leaky(h1 @ w2 + b2)
// 128 threads; block = 16 points (64 edge rows) x 192 cols; BK=8; micro 8x12.
__global__ __launch_bounds__(128) void edge_stage2(
    const float* __restrict__ UV, const int* __restrict__ idx,
    const float* __restrict__ w2, const float* __restrict__ b2,
    float* __restrict__ out, int H1) {
  __shared__ float sH[8][68];
  __shared__ float sW[8][200];
  __shared__ int sJ[64];
  int tid = threadIdx.x;
  int g0 = blockIdx.x * 16;               // chunk-local first point (one batch per block)
  int bbase = (g0 >> 8) << 8;
  if (tid < 64) sJ[tid] = bbase + idx[(size_t)g0 * 4 + tid];
  __syncthreads();
  int W2 = H1 * 2;
  int rS = tid >> 1, segS = tid & 1;      // staging: edge row 0..63, k-half 0/1
  int gp_r = g0 + (rS >> 2);
  int jr = sJ[rS];
  const float* upB = UV + (size_t)gp_r * W2;
  const float* vpB = UV + (size_t)jr * W2 + H1;
  int ty = tid >> 4, tx = tid & 15;       // compute: rows ty*8.., cols tx*12..
  float acc[8][12] = {};
  int nKt = (H1 + 7) >> 3;
  for (int kt = 0; kt < nKt; ++kt) {
    int k0 = kt << 3;
    // stage sH[kk][row]
    {
      int c = k0 + (segS << 2);
      float u[4], v[4];
      if (c + 3 < H1) {
        float4 uu = *(const float4*)(upB + c);
        float4 vv = *(const float4*)(vpB + c);
        u[0]=uu.x; u[1]=uu.y; u[2]=uu.z; u[3]=uu.w;
        v[0]=vv.x; v[1]=vv.y; v[2]=vv.z; v[3]=vv.w;
      } else {
        #pragma unroll
        for (int j = 0; j < 4; ++j) {
          u[j] = (c + j < H1) ? upB[c + j] : 0.f;
          v[j] = (c + j < H1) ? vpB[c + j] : 0.f;
        }
      }
      #pragma unroll
      for (int j = 0; j < 4; ++j) {
        float t = u[j] + v[j];
        sH[(segS << 2) + j][rS] = (c + j < H1) ? LK(t) : 0.f;
      }
    }
    // stage sW: 8 x 192 = 384 float4, 3 per thread
    #pragma unroll
    for (int p = 0; p < 3; ++p) {
      int q = tid + (p << 7);             // 0..383
      int kk = q / 48, c4 = q - kk * 48;
      int k = k0 + kk;
      float4 wv = {0.f, 0.f, 0.f, 0.f};
      if (k < H1) wv = *(const float4*)(w2 + (size_t)k * 192 + (c4 << 2));
      *(float4*)&sW[kk][c4 << 2] = wv;
    }
    __syncthreads();
    #pragma unroll
    for (int kk = 0; kk < 8; ++kk) {
      float4 a0 = *(const float4*)&sH[kk][ty * 8];
      float4 a1 = *(const float4*)&sH[kk][ty * 8 + 4];
      float av[8] = {a0.x,a0.y,a0.z,a0.w,a1.x,a1.y,a1.z,a1.w};
      float wv[12];
      #pragma unroll
      for (int t3 = 0; t3 < 3; ++t3) {
        float4 w = *(const float4*)&sW[kk][tx * 12 + t3 * 4];
        wv[t3*4+0]=w.x; wv[t3*4+1]=w.y; wv[t3*4+2]=w.z; wv[t3*4+3]=w.w;
      }
      #pragma unroll
      for (int i = 0; i < 8; ++i)
        #pragma unroll
        for (int j = 0; j < 12; ++j)
          acc[i][j] += av[i] * wv[j];
    }
    __syncthreads();
  }
  // epilogue: 2 points per thread, sum 4 edges each
  #pragma unroll
  for (int pp = 0; pp < 2; ++pp) {
    int gp = g0 + ty * 2 + pp;
    float o[12];
    #pragma unroll
    for (int j = 0; j < 12; ++j) {
      float bvv = b2[tx * 12 + j];
      float s = 0.f;
      #pragma unroll
      for (int i = 0; i < 4; ++i) {
        float t = acc[pp * 4 + i][j] + bvv;
        s += LK(t);
      }
      o[j] = s;
    }
    float* op = out + (size_t)gp * 192 + tx * 12;
    float4 o0 = {o[0], o[1], o[2], o[3]};
    float4 o1 = {o[4], o[5], o[6], o[7]};
    float4 o2 = {o[8], o[9], o[10], o[11]};
    *(float4*)(op)     = o0;
    *(float4*)(op + 4) = o1;
    *(float4*)(op + 8) = o2;
  }
}

// ---------------- pooling: max/min/sum/mean over N, then leaky ----------------
__global__ void pool_kernel(const float* __restrict__ h, float* __restrict__ pooled) {
  int b = blockIdx.x, ch = threadIdx.x;  // 192 threads
  const float* p = h + (size_t)b * N_ * 192 + ch;
  float mx = -INFINITY, mn = INFINITY, sm = 0.f;
  for (int n = 0; n < N_; ++n) {
    float v = p[(size_t)n * 192];
    mx = fmaxf(mx, v); mn = fminf(mn, v); sm += v;
  }
  float* o = pooled + (size_t)b * 768;
  o[ch]       = LK(mx);
  o[192 + ch] = LK(mn);
  o[384 + ch] = LK(sm);
  float mean = sm * (1.f / 256.f);
  o[576 + ch] = LK(mean);
}

// ---------------- head: nn3 (768->96) + leaky + nn4 (96->1) ----------------
__global__ void head_kernel(const float* __restrict__ pooled,
                            const float* __restrict__ w3, const float* __restrict__ b3,
                            const float* __restrict__ w4, const float* __restrict__ b4,
                            float* __restrict__ out) {
  __shared__ float sp[768];
  __shared__ float st[96];
  int b = blockIdx.x, t = threadIdx.x;   // 128 threads
  for (int c = t; c < 768; c += 128) sp[c] = pooled[(size_t)b * 768 + c];
  __syncthreads();
  if (t < 96) {
    float s = b3[t];
    for (int r = 0; r < 768; ++r) s += sp[r] * w3[(size_t)r * 96 + t];
    s = LK(s);
    st[t] = s * w4[t];
  }
  __syncthreads();
  if (t == 0) {
    float s = b4[0];
    for (int i = 0; i < 96; ++i) s += st[i];
    out[b] = s;
  }
}

extern "C" void kernel_launch(void* const* d_in, const int* in_sizes, int n_in,
                              void* d_out, int out_size, void* d_ws, size_t ws_size,
                              hipStream_t stream) {
  (void)in_sizes; (void)n_in; (void)out_size; (void)ws_size;
  const float* x = (const float*)d_in[0];
  const float* P[25];
  for (int i = 0; i < 25; ++i) P[i] = (const float*)d_in[i];

  // ---- workspace layout (peak ~202.1 MB) ----
  char* ws = (char*)d_ws;
  int*   idx    = (int*)  (ws + 0);            //  1,048,576
  float* A      = (float*)(ws + 1048576);      // 50,331,648  (a, then c, then h2)
  float* Bb     = (float*)(ws + 51380224);     // 50,331,648  (b, then d)
  float* h1     = (float*)(ws + 101711872);    // 66,060,288
  float* UV     = (float*)(ws + 167772160);    // 33,030,144  (chunk, [U|V] stride 2*H1)
  float* pooled = (float*)(ws + 200802304);    //    786,432
  float* wcat   = (float*)(ws + 201588736);    //    508,032
  float* bcat   = (float*)(ws + 202096768);    //      2,016

  auto edge_layer = [&](const float* src, int F, const float* w1, const float* b1,
                        const float* w2, const float* b2, float* dst, int H1) {
    knn_kernel<<<B_, N_, 0, stream>>>(src, F, idx);
    prep_uvw<<<(F * H1 + 255) / 256, 256, 0, stream>>>(w1, b1, F, H1, wcat, bcat);
    int W2 = 2 * H1;
    dim3 gUV((W2 + 127) / 128, CHUNK_ROWS / 64);
    for (int cb = 0; cb < B_; cb += CHUNK_B) {
      size_t base = (size_t)cb * N_;
      // UV = src @ [wdiff | w1_bot] + [b1 | 0]
      gemm_t<64, false, false, true><<<gUV, 128, 0, stream>>>(src + base * F, wcat, bcat, UV, CHUNK_ROWS, W2, F);
      edge_stage2<<<CHUNK_ROWS / 16, 128, 0, stream>>>(UV, idx + base * 4, w2, b2, dst + base * 192, H1);
    }
  };

  // a = edge(x) -> A ; b = edge(a) -> Bb
  edge_layer(x,  4,   P[1], P[2], P[3], P[4], A,  96);
  edge_layer(A,  192, P[5], P[6], P[7], P[8], Bb, 252);
  // h1 = [x,a,b] @ nn1w[0:388] + nn1b   (x prologue + aligned segments)
  {
    dim3 g(2, BN / 128);
    gemm_nn1<true><<<g, 256, 0, stream>>>(A, Bb, x, P[17], P[17] + 4 * 252, P[18], h1, BN, 252);
  }
  // c = edge(b) -> A ; d = edge(c) -> Bb
  edge_layer(Bb, 192, P[9],  P[10], P[11], P[12], A,  252);
  edge_layer(A,  192, P[13], P[14], P[15], P[16], Bb, 252);
  // h1 += [c,d] @ nn1w[388:772]
  {
    dim3 g(2, BN / 128);
    gemm_nn1<false><<<g, 256, 0, stream>>>(A, Bb, nullptr, nullptr, P[17] + (size_t)388 * 252, nullptr, h1, BN, 252);
  }
  // nn2: h2 = leaky(h1) @ nn2w + nn2b -> A
  {
    dim3 g(2, BN / 128);
    gemm_t<128, true, false, true><<<g, 256, 0, stream>>>(h1, P[19], P[20], A, BN, 192, 252);
  }
  pool_kernel<<<B_, 192, 0, stream>>>(A, pooled);
  head_kernel<<<B_, 128, 0, stream>>>(pooled, P[21], P[22], P[23], P[24], (float*)d_out);
}

// Round 6
// 2198.882 us; speedup vs baseline: 1.5123x; 1.5123x over previous
//
#include <hip/hip_runtime.h>
#include <cstdint>
#include <cstddef>

#define LK(x) ((x) > 0.f ? (x) : 0.01f * (x))

typedef _Float16 f16x8 __attribute__((ext_vector_type(8)));
typedef _Float16 f16x4 __attribute__((ext_vector_type(4)));
typedef float f32x4 __attribute__((ext_vector_type(4)));

constexpr int B_ = 256;
constexpr int N_ = 256;
constexpr int BN = B_ * N_;
constexpr int CHUNK_B = 64;                 // batches per UV chunk
constexpr int CHUNK_ROWS = CHUNK_B * N_;    // 16384 rows

__device__ inline void dec2(float v, _Float16& h, _Float16& l) {
  _Float16 hh = (_Float16)v;
  h = hh;
  l = (_Float16)(v - (float)hh);
}

// ---------------- KNN: one block per batch, one thread per point ----------------
__global__ void knn_kernel(const float* __restrict__ feat, int F, int* __restrict__ idxout) {
  __shared__ float px[N_], py[N_], pz[N_];
  int b = blockIdx.x, t = threadIdx.x;
  const float* row = feat + ((size_t)b * N_ + t) * F;
  px[t] = row[0]; py[t] = row[1]; pz[t] = row[2];
  __syncthreads();
  float x = px[t], y = py[t], z = pz[t];
  float bd0 = INFINITY, bd1 = INFINITY, bd2 = INFINITY, bd3 = INFINITY;
  int bi0 = 0, bi1 = 0, bi2 = 0, bi3 = 0;
  for (int j = 0; j < N_; ++j) {
    #pragma clang fp contract(off)
    float dx = x - px[j], dy = y - py[j], dz = z - pz[j];
    float d = (dx * dx + dy * dy) + dz * dz;
    if (j == t) continue;
    if (d < bd3) {
      if (d < bd2) {
        bd3 = bd2; bi3 = bi2;
        if (d < bd1) {
          bd2 = bd1; bi2 = bi1;
          if (d < bd0) { bd1 = bd0; bi1 = bi0; bd0 = d; bi0 = j; }
          else         { bd1 = d; bi1 = j; }
        } else         { bd2 = d; bi2 = j; }
      } else           { bd3 = d; bi3 = j; }
    }
  }
  int* o = idxout + ((size_t)b * N_ + t) * 4;
  o[0] = bi0; o[1] = bi1; o[2] = bi2; o[3] = bi3;
}

// ============================ fp32 path (layers 1-3) ============================

// wcat = [w1_top - w1_bot | w1_bot] (F x 2H1), bcat = [b1 | 0]
__global__ void prep_uvw(const float* __restrict__ w1, const float* __restrict__ b1,
                         int F, int H1, float* __restrict__ wcat, float* __restrict__ bcat) {
  int t = blockIdx.x * 256 + threadIdx.x;
  int FH = F * H1;
  if (t < FH) {
    int k = t / H1, c = t - k * H1;
    float top = w1[(size_t)k * H1 + c];
    float bot = w1[(size_t)(F + k) * H1 + c];
    wcat[(size_t)k * 2 * H1 + c]      = top - bot;
    wcat[(size_t)k * 2 * H1 + H1 + c] = bot;
  }
  if (t < H1) { bcat[t] = b1[t]; bcat[H1 + t] = 0.f; }
}

// fp32 GEMM: 128x64 tile, BK=16, 256 thr, 8x4 micro (R3 verbatim)
template<bool ACT_A, bool ACCUM, bool HAS_BIAS>
__global__ __launch_bounds__(256) void gemm_f32(
    const float* __restrict__ A, const float* __restrict__ W,
    const float* __restrict__ bias, float* __restrict__ C,
    int M, int N, int K) {
  __shared__ float sA[16][132];
  __shared__ float sW[16][68];
  int tid = threadIdx.x;
  int m0 = blockIdx.y * 128;
  int n0 = blockIdx.x * 64;
  int kkA = tid & 15, mA = tid >> 4;
  int nW = tid & 63, kW = tid >> 6;
  int ty = tid >> 4, tx = tid & 15;
  float acc[8][4] = {};
  for (int k0 = 0; k0 < K; k0 += 16) {
    int kg = k0 + kkA;
    #pragma unroll
    for (int i = 0; i < 8; ++i) {
      int m = mA + i * 16;
      float v = 0.f;
      if (kg < K) {
        v = A[(size_t)(m0 + m) * K + kg];
        if (ACT_A) v = LK(v);
      }
      sA[kkA][m] = v;
    }
    #pragma unroll
    for (int q = 0; q < 4; ++q) {
      int kk = kW + q * 4;
      int kgw = k0 + kk, n = n0 + nW;
      float v = 0.f;
      if (kgw < K && n < N) v = W[(size_t)kgw * N + n];
      sW[kk][nW] = v;
    }
    __syncthreads();
    #pragma unroll
    for (int kk = 0; kk < 16; ++kk) {
      float4 a0 = *(const float4*)&sA[kk][ty * 8];
      float4 a1 = *(const float4*)&sA[kk][ty * 8 + 4];
      float4 w  = *(const float4*)&sW[kk][tx * 4];
      float av[8] = {a0.x, a0.y, a0.z, a0.w, a1.x, a1.y, a1.z, a1.w};
      float wv[4] = {w.x, w.y, w.z, w.w};
      #pragma unroll
      for (int i = 0; i < 8; ++i)
        #pragma unroll
        for (int j = 0; j < 4; ++j)
          acc[i][j] += av[i] * wv[j];
    }
    __syncthreads();
  }
  int n = n0 + tx * 4;
  float bv[4] = {0.f, 0.f, 0.f, 0.f};
  if (HAS_BIAS) {
    #pragma unroll
    for (int j = 0; j < 4; ++j) if (n + j < N) bv[j] = bias[n + j];
  }
  #pragma unroll
  for (int i = 0; i < 8; ++i) {
    size_t m = (size_t)(m0 + ty * 8 + i);
    if (n + 3 < N) {
      float4 o;
      o.x = acc[i][0] + bv[0]; o.y = acc[i][1] + bv[1];
      o.z = acc[i][2] + bv[2]; o.w = acc[i][3] + bv[3];
      float4* cp = (float4*)(C + m * N + n);
      if (ACCUM) { float4 c = *cp; o.x += c.x; o.y += c.y; o.z += c.z; o.w += c.w; }
      *cp = o;
    } else {
      #pragma unroll
      for (int j = 0; j < 4; ++j) {
        if (n + j < N) {
          float v = acc[i][j] + bv[j];
          size_t off = m * N + n + j;
          if (ACCUM) v += C[off];
          C[off] = v;
        }
      }
    }
  }
}

// fp32 fused edge stage 2, K-tiled (R3 verbatim)
__global__ __launch_bounds__(256) void edge_stage2(
    const float* __restrict__ UV, const int* __restrict__ idx,
    const float* __restrict__ w2, const float* __restrict__ b2,
    float* __restrict__ out, int H1) {
  __shared__ float sH[16][68];
  __shared__ float sW[16][196];
  __shared__ int sJ[64];
  int tid = threadIdx.x;
  int g0 = blockIdx.x * 16;
  int bbase = (g0 >> 8) << 8;
  if (tid < 64) sJ[tid] = bbase + idx[(size_t)g0 * 4 + tid];
  int W2 = H1 * 2;
  int r = tid >> 2, seg = tid & 3;
  int gp_r = g0 + (r >> 2);
  int ty = tid >> 4, tx = tid & 15;
  int gp = g0 + ty;
  float acc[4][12] = {};
  int nKt = (H1 + 15) >> 4;
  for (int kt = 0; kt < nKt; ++kt) {
    int k0 = kt << 4;
    __syncthreads();
    {
      int c = k0 + (seg << 2);
      const float* up = UV + (size_t)gp_r * W2 + c;
      const float* vp = UV + (size_t)sJ[r] * W2 + H1 + c;
      float u[4], v[4];
      if (c + 3 < H1) {
        float4 uu = *(const float4*)up; float4 vv = *(const float4*)vp;
        u[0] = uu.x; u[1] = uu.y; u[2] = uu.z; u[3] = uu.w;
        v[0] = vv.x; v[1] = vv.y; v[2] = vv.z; v[3] = vv.w;
      } else {
        #pragma unroll
        for (int j = 0; j < 4; ++j) {
          u[j] = (c + j < H1) ? up[j] : 0.f;
          v[j] = (c + j < H1) ? vp[j] : 0.f;
        }
      }
      #pragma unroll
      for (int j = 0; j < 4; ++j) {
        float t = u[j] + v[j];
        sH[(seg << 2) + j][r] = (c + j < H1) ? LK(t) : 0.f;
      }
    }
    #pragma unroll
    for (int p = 0; p < 3; ++p) {
      int q = tid + (p << 8);
      int kk = q / 48;
      int c4 = q - kk * 48;
      int k = k0 + kk;
      float4 wv = {0.f, 0.f, 0.f, 0.f};
      if (k < H1) wv = *(const float4*)(w2 + (size_t)k * 192 + (c4 << 2));
      *(float4*)&sW[kk][c4 << 2] = wv;
    }
    __syncthreads();
    #pragma unroll
    for (int kk = 0; kk < 16; ++kk) {
      float4 a = *(const float4*)&sH[kk][ty << 2];
      float av[4] = {a.x, a.y, a.z, a.w};
      #pragma unroll
      for (int ct = 0; ct < 3; ++ct) {
        float4 w = *(const float4*)&sW[kk][ct * 64 + (tx << 2)];
        float wv[4] = {w.x, w.y, w.z, w.w};
        #pragma unroll
        for (int i = 0; i < 4; ++i)
          #pragma unroll
          for (int j = 0; j < 4; ++j)
            acc[i][ct * 4 + j] += av[i] * wv[j];
      }
    }
  }
  #pragma unroll
  for (int ct = 0; ct < 3; ++ct) {
    float o[4];
    #pragma unroll
    for (int j = 0; j < 4; ++j) {
      int col = ct * 64 + (tx << 2) + j;
      float bvv = b2[col];
      float s = 0.f;
      #pragma unroll
      for (int i = 0; i < 4; ++i) {
        float t = acc[i][ct * 4 + j] + bvv;
        s += LK(t);
      }
      o[j] = s;
    }
    float4 ov = {o[0], o[1], o[2], o[3]};
    *(float4*)(out + (size_t)gp * 192 + ct * 64 + (tx << 2)) = ov;
  }
}

// ============================ fp16x3 MFMA path ============================

// Wp[n][k-octets]: [8 hi | 8 lo] per octet; [wdiff | wbot] transposed. bcat = [b1|0]
__global__ void prep_wcatT(const float* __restrict__ w1, const float* __restrict__ b1,
                           int F, int H1, int Fpad, _Float16* __restrict__ Wp,
                           float* __restrict__ bcat) {
  int t = blockIdx.x * 256 + threadIdx.x;
  int NN = 2 * H1;
  if (t < NN * Fpad) {
    int n = t / Fpad, k = t - n * Fpad;
    float v = 0.f;
    if (k < F) {
      if (n < H1) v = w1[(size_t)k * H1 + n] - w1[(size_t)(F + k) * H1 + n];
      else        v = w1[(size_t)(F + k) * H1 + (n - H1)];
    }
    _Float16 h, l; dec2(v, h, l);
    size_t base = (size_t)n * 2 * Fpad + (size_t)(k >> 3) * 16 + (k & 7);
    Wp[base] = h; Wp[base + 8] = l;
  }
  if (t < NN) bcat[t] = (t < H1) ? b1[t] : 0.f;
}

// generic W[K][N] -> Wp[N][2*Kpad] transposed + decomposed + octet-interleaved
__global__ void prep_wT(const float* __restrict__ W, int K, int N, int Kpad,
                        _Float16* __restrict__ Wp) {
  int t = blockIdx.x * 256 + threadIdx.x;
  if (t >= N * Kpad) return;
  int n = t / Kpad, k = t - n * Kpad;
  float v = (k < K) ? W[(size_t)k * N + n] : 0.f;
  _Float16 h, l; dec2(v, h, l);
  size_t base = (size_t)n * 2 * Kpad + (size_t)(k >> 3) * 16 + (k & 7);
  Wp[base] = h; Wp[base + 8] = l;
}

// fp16x3 MFMA GEMM: C (+)= act?(A) @ W (+ bias). Block 128x128, 4 waves, K-step 32.
// A = [A0 (w0 cols) | A1 (K-w0 cols)] row-major; w0 % 32 == 0 (or w0 == K).
template<bool ACT_A, bool ACCUM, bool HAS_BIAS>
__global__ __launch_bounds__(256) void gemm3h(
    const float* __restrict__ A0, const float* __restrict__ A1, int w0,
    const _Float16* __restrict__ Wp, const float* __restrict__ bias,
    float* __restrict__ C, int M, int N, int K, int Kpad) {
  __shared__ _Float16 sA[128 * 72];
  __shared__ _Float16 sB[128 * 72];
  int tid = threadIdx.x;
  int m0 = blockIdx.y * 128, n0 = blockIdx.x * 128;
  int lane = tid & 63, wid = tid >> 6;
  int wy = wid >> 1, wx = wid & 1;
  int lm = lane & 15, lq = lane >> 4;
  int rA = tid >> 1, qA = (tid & 1) * 4;
  f32x4 acc[4][4];
  #pragma unroll
  for (int i = 0; i < 4; ++i)
    #pragma unroll
    for (int j = 0; j < 4; ++j) acc[i][j] = 0.f;

  for (int k0 = 0; k0 < Kpad; k0 += 32) {
    __syncthreads();
    {
      const float* Ap; int kb, wA;
      if (k0 < w0) { Ap = A0; kb = k0;      wA = w0; }
      else         { Ap = A1; kb = k0 - w0; wA = K - w0; }
      const float* arow = Ap + (size_t)(m0 + rA) * wA;
      #pragma unroll
      for (int qi = 0; qi < 4; ++qi) {
        int q = qA + qi;
        int kl = kb + q * 4;
        float4 v = {0.f, 0.f, 0.f, 0.f};
        if (kl + 3 < wA) v = *(const float4*)(arow + kl);
        else {
          if (kl + 0 < wA) v.x = arow[kl + 0];
          if (kl + 1 < wA) v.y = arow[kl + 1];
          if (kl + 2 < wA) v.z = arow[kl + 2];
        }
        if (ACT_A) { v.x = LK(v.x); v.y = LK(v.y); v.z = LK(v.z); v.w = LK(v.w); }
        _Float16 h0,h1,h2,h3,l0,l1,l2,l3;
        dec2(v.x,h0,l0); dec2(v.y,h1,l1); dec2(v.z,h2,l2); dec2(v.w,h3,l3);
        int off = rA * 72 + (q >> 1) * 16 + (q & 1) * 4;
        f16x4 th; th[0]=h0; th[1]=h1; th[2]=h2; th[3]=h3;
        f16x4 tl; tl[0]=l0; tl[1]=l1; tl[2]=l2; tl[3]=l3;
        *(f16x4*)&sA[off]     = th;
        *(f16x4*)&sA[off + 8] = tl;
      }
    }
    {
      int n = n0 + rA;
      const _Float16* src = Wp + (size_t)n * 2 * Kpad + (size_t)k0 * 2;
      #pragma unroll
      for (int ui = 0; ui < 4; ++ui) {
        int u = (tid & 1) * 4 + ui;
        float4 v = {0.f, 0.f, 0.f, 0.f};
        if (n < N) v = *(const float4*)(src + u * 8);
        *(float4*)&sB[rA * 72 + u * 8] = v;
      }
    }
    __syncthreads();
    f16x8 af[4][2], bf[4][2];
    #pragma unroll
    for (int mt = 0; mt < 4; ++mt) {
      int row = wy * 64 + mt * 16 + lm;
      af[mt][0] = *(const f16x8*)&sA[row * 72 + lq * 16];
      af[mt][1] = *(const f16x8*)&sA[row * 72 + lq * 16 + 8];
    }
    #pragma unroll
    for (int nt = 0; nt < 4; ++nt) {
      int row = wx * 64 + nt * 16 + lm;
      bf[nt][0] = *(const f16x8*)&sB[row * 72 + lq * 16];
      bf[nt][1] = *(const f16x8*)&sB[row * 72 + lq * 16 + 8];
    }
    #pragma unroll
    for (int mt = 0; mt < 4; ++mt)
      #pragma unroll
      for (int nt = 0; nt < 4; ++nt) {
        acc[mt][nt] = __builtin_amdgcn_mfma_f32_16x16x32_f16(af[mt][0], bf[nt][0], acc[mt][nt], 0, 0, 0);
        acc[mt][nt] = __builtin_amdgcn_mfma_f32_16x16x32_f16(af[mt][0], bf[nt][1], acc[mt][nt], 0, 0, 0);
        acc[mt][nt] = __builtin_amdgcn_mfma_f32_16x16x32_f16(af[mt][1], bf[nt][0], acc[mt][nt], 0, 0, 0);
      }
  }
  #pragma unroll
  for (int mt = 0; mt < 4; ++mt) {
    #pragma unroll
    for (int nt = 0; nt < 4; ++nt) {
      int n = n0 + wx * 64 + nt * 16 + lm;
      if (n >= N) continue;
      float bv = HAS_BIAS ? bias[n] : 0.f;
      #pragma unroll
      for (int r = 0; r < 4; ++r) {
        size_t m = (size_t)m0 + wy * 64 + mt * 16 + lq * 4 + r;
        float v = acc[mt][nt][r] + bv;
        size_t off = m * N + n;
        if (ACCUM) v += C[off];
        C[off] = v;
      }
    }
  }
}

// fp16x3 fused edge stage 2. 256 thr = 16 points = 64 edge rows x 192 cols.
__global__ __launch_bounds__(256) void edge_stage2_m(
    const float* __restrict__ UV, const int* __restrict__ idx,
    const _Float16* __restrict__ Wp, const float* __restrict__ b2,
    float* __restrict__ out, int H1, int Kpad) {
  __shared__ _Float16 sH[64 * 72];
  __shared__ _Float16 sW[192 * 72];
  __shared__ int sJ[64];
  int tid = threadIdx.x;
  int g0 = blockIdx.x * 16;
  int bbase = (g0 >> 8) << 8;
  if (tid < 64) sJ[tid] = bbase + idx[(size_t)g0 * 4 + tid];
  int W2 = 2 * H1;
  int lane = tid & 63, w = tid >> 6;
  int lm = lane & 15, lq = lane >> 4;
  int rS = tid >> 2, qS = tid & 3;
  f32x4 acc[4][3];
  #pragma unroll
  for (int i = 0; i < 4; ++i)
    #pragma unroll
    for (int j = 0; j < 3; ++j) acc[i][j] = 0.f;

  for (int k0 = 0; k0 < Kpad; k0 += 32) {
    __syncthreads();
    {
      int gp_r = g0 + (rS >> 2);
      int jr = sJ[rS];
      const float* up = UV + (size_t)gp_r * W2;
      const float* vp = UV + (size_t)jr * W2 + H1;
      #pragma unroll
      for (int hf = 0; hf < 2; ++hf) {
        int k = k0 + qS * 8 + hf * 4;
        float4 u = {0.f,0.f,0.f,0.f}, v = {0.f,0.f,0.f,0.f};
        if (k + 3 < H1) { u = *(const float4*)(up + k); v = *(const float4*)(vp + k); }
        else {
          if (k + 0 < H1) { u.x = up[k+0]; v.x = vp[k+0]; }
          if (k + 1 < H1) { u.y = up[k+1]; v.y = vp[k+1]; }
          if (k + 2 < H1) { u.z = up[k+2]; v.z = vp[k+2]; }
        }
        float e0 = LK(u.x + v.x), e1 = LK(u.y + v.y), e2 = LK(u.z + v.z), e3 = LK(u.w + v.w);
        _Float16 h0,h1,h2,h3,l0,l1,l2,l3;
        dec2(e0,h0,l0); dec2(e1,h1,l1); dec2(e2,h2,l2); dec2(e3,h3,l3);
        int off = rS * 72 + qS * 16 + hf * 4;
        f16x4 th; th[0]=h0; th[1]=h1; th[2]=h2; th[3]=h3;
        f16x4 tl; tl[0]=l0; tl[1]=l1; tl[2]=l2; tl[3]=l3;
        *(f16x4*)&sH[off]     = th;
        *(f16x4*)&sH[off + 8] = tl;
      }
    }
    {
      const _Float16* src = Wp + (size_t)k0 * 2;
      #pragma unroll
      for (int p = 0; p < 6; ++p) {
        int e = tid + p * 256;
        int n = e >> 3, u = e & 7;
        *(float4*)&sW[n * 72 + u * 8] =
            *(const float4*)(src + (size_t)n * 2 * Kpad + u * 8);
      }
    }
    __syncthreads();
    f16x8 af[4][2], bf[3][2];
    #pragma unroll
    for (int mt = 0; mt < 4; ++mt) {
      int row = mt * 16 + lm;
      af[mt][0] = *(const f16x8*)&sH[row * 72 + lq * 16];
      af[mt][1] = *(const f16x8*)&sH[row * 72 + lq * 16 + 8];
    }
    #pragma unroll
    for (int t3 = 0; t3 < 3; ++t3) {
      int row = (w * 3 + t3) * 16 + lm;
      bf[t3][0] = *(const f16x8*)&sW[row * 72 + lq * 16];
      bf[t3][1] = *(const f16x8*)&sW[row * 72 + lq * 16 + 8];
    }
    #pragma unroll
    for (int mt = 0; mt < 4; ++mt)
      #pragma unroll
      for (int t3 = 0; t3 < 3; ++t3) {
        acc[mt][t3] = __builtin_amdgcn_mfma_f32_16x16x32_f16(af[mt][0], bf[t3][0], acc[mt][t3], 0, 0, 0);
        acc[mt][t3] = __builtin_amdgcn_mfma_f32_16x16x32_f16(af[mt][0], bf[t3][1], acc[mt][t3], 0, 0, 0);
        acc[mt][t3] = __builtin_amdgcn_mfma_f32_16x16x32_f16(af[mt][1], bf[t3][0], acc[mt][t3], 0, 0, 0);
      }
  }
  #pragma unroll
  for (int mt = 0; mt < 4; ++mt) {
    int gp = g0 + mt * 4 + lq;
    #pragma unroll
    for (int t3 = 0; t3 < 3; ++t3) {
      int col = (w * 3 + t3) * 16 + lm;
      float bv = b2[col];
      float s = 0.f;
      #pragma unroll
      for (int r = 0; r < 4; ++r) s += LK(acc[mt][t3][r] + bv);
      out[(size_t)gp * 192 + col] = s;
    }
  }
}

// ---------------- nn1 init: h1 = x @ Wx(4x252) + b ----------------
__global__ __launch_bounds__(256) void nn1_init(const float* __restrict__ x,
                                                const float* __restrict__ Wx,
                                                const float* __restrict__ b,
                                                float* __restrict__ h1) {
  __shared__ float sX[64][4];
  __shared__ float sW[4][256];
  int tid = threadIdx.x;
  int r0 = blockIdx.x * 64;
  if (tid < 64) *(float4*)sX[tid] = *(const float4*)(x + (size_t)(r0 + tid) * 4);
  for (int e = tid; e < 1024; e += 256) {
    int k = e >> 8, n = e & 255;
    sW[k][n] = (n < 252) ? Wx[(size_t)k * 252 + n] : 0.f;
  }
  __syncthreads();
  int cg = tid & 63, rr = tid >> 6;
  if (cg < 63) {
    #pragma unroll 4
    for (int i = 0; i < 16; ++i) {
      int rl = rr + i * 4;
      float x0 = sX[rl][0], x1 = sX[rl][1], x2 = sX[rl][2], x3 = sX[rl][3];
      float4 o;
      int c = cg * 4;
      o.x = b[c+0] + x0*sW[0][c+0] + x1*sW[1][c+0] + x2*sW[2][c+0] + x3*sW[3][c+0];
      o.y = b[c+1] + x0*sW[0][c+1] + x1*sW[1][c+1] + x2*sW[2][c+1] + x3*sW[3][c+1];
      o.z = b[c+2] + x0*sW[0][c+2] + x1*sW[1][c+2] + x2*sW[2][c+2] + x3*sW[3][c+2];
      o.w = b[c+3] + x0*sW[0][c+3] + x1*sW[1][c+3] + x2*sW[2][c+3] + x3*sW[3][c+3];
      *(float4*)(h1 + (size_t)(r0 + rl) * 252 + c) = o;
    }
  }
}

// ---------------- pooling ----------------
__global__ void pool_kernel(const float* __restrict__ h, float* __restrict__ pooled) {
  int b = blockIdx.x, ch = threadIdx.x;  // 192 threads
  const float* p = h + (size_t)b * N_ * 192 + ch;
  float mx = -INFINITY, mn = INFINITY, sm = 0.f;
  for (int n = 0; n < N_; ++n) {
    float v = p[(size_t)n * 192];
    mx = fmaxf(mx, v); mn = fminf(mn, v); sm += v;
  }
  float* o = pooled + (size_t)b * 768;
  o[ch]       = LK(mx);
  o[192 + ch] = LK(mn);
  o[384 + ch] = LK(sm);
  o[576 + ch] = LK(sm * (1.f / 256.f));
}

// ---------------- head ----------------
__global__ void head_kernel(const float* __restrict__ pooled,
                            const float* __restrict__ w3, const float* __restrict__ b3,
                            const float* __restrict__ w4, const float* __restrict__ b4,
                            float* __restrict__ out) {
  __shared__ float sp[768];
  __shared__ float st[96];
  int b = blockIdx.x, t = threadIdx.x;   // 128 threads
  for (int c = t; c < 768; c += 128) sp[c] = pooled[(size_t)b * 768 + c];
  __syncthreads();
  if (t < 96) {
    float s = b3[t];
    for (int r = 0; r < 768; ++r) s += sp[r] * w3[(size_t)r * 96 + t];
    s = LK(s);
    st[t] = s * w4[t];
  }
  __syncthreads();
  if (t == 0) {
    float s = b4[0];
    for (int i = 0; i < 96; ++i) s += st[i];
    out[b] = s;
  }
}

extern "C" void kernel_launch(void* const* d_in, const int* in_sizes, int n_in,
                              void* d_out, int out_size, void* d_ws, size_t ws_size,
                              hipStream_t stream) {
  (void)in_sizes; (void)n_in; (void)out_size; (void)ws_size;
  const float* x = (const float*)d_in[0];
  const float* P[25];
  for (int i = 0; i < 25; ++i) P[i] = (const float*)d_in[i];

  // ---- workspace layout (peak ~202.6 MB) ----
  char* ws = (char*)d_ws;
  int*       idx    = (int*)      (ws + 0);            //  1,048,576
  float*     A      = (float*)    (ws + 1048576);      // 50,331,648  (a, c, then h2)
  float*     Bb     = (float*)    (ws + 51380224);     // 50,331,648  (b, then d)
  float*     h1     = (float*)    (ws + 101711872);    // 66,060,288
  float*     UV     = (float*)    (ws + 167772160);    // 33,030,144  (chunk [U|V])
  float*     pooled = (float*)    (ws + 200802304);    //    786,432
  char*      WSH1   =             (ws + 201588736);    //    524,288  (fp32 wcat OR fp16 WB1)
  _Float16*  WB2    = (_Float16*) (ws + 202113024);    //    524,288
  float*     bcat   = (float*)    (ws + 202637312);    //      4,096

  float*    wcat = (float*)   WSH1;
  _Float16* WB1  = (_Float16*)WSH1;

  // ---- fp32 edge layer (KNN-feeding layers: exact R3 arithmetic) ----
  auto edge_layer_f32 = [&](const float* src, int F, int H1,
                            const float* w1, const float* b1,
                            const float* w2, const float* b2, float* dst) {
    knn_kernel<<<B_, N_, 0, stream>>>(src, F, idx);
    prep_uvw<<<(F * H1 + 255) / 256, 256, 0, stream>>>(w1, b1, F, H1, wcat, bcat);
    int W2 = 2 * H1;
    dim3 gUV((W2 + 63) / 64, CHUNK_ROWS / 128);
    for (int cb = 0; cb < B_; cb += CHUNK_B) {
      size_t base = (size_t)cb * N_;
      gemm_f32<false, false, true><<<gUV, 256, 0, stream>>>(src + base * F, wcat, bcat, UV, CHUNK_ROWS, W2, F);
      edge_stage2<<<CHUNK_ROWS / 16, 256, 0, stream>>>(UV, idx + base * 4, w2, b2, dst + base * 192, H1);
    }
  };

  // ---- fp16x3 edge layer (layer 4 only: output feeds no KNN) ----
  auto edge_layer_f16 = [&](const float* src, int F, int H1,
                            const float* w1, const float* b1,
                            const float* w2, const float* b2, float* dst) {
    int Fpad = (F + 31) & ~31;
    int KpadW2 = (H1 + 31) & ~31;
    int NN = 2 * H1;
    knn_kernel<<<B_, N_, 0, stream>>>(src, F, idx);
    prep_wcatT<<<(NN * Fpad + 255) / 256, 256, 0, stream>>>(w1, b1, F, H1, Fpad, WB1, bcat);
    prep_wT<<<(192 * KpadW2 + 255) / 256, 256, 0, stream>>>(w2, H1, 192, KpadW2, WB2);
    dim3 gUV((NN + 127) / 128, CHUNK_ROWS / 128);
    for (int cb = 0; cb < B_; cb += CHUNK_B) {
      size_t base = (size_t)cb * N_;
      gemm3h<false, false, true><<<gUV, 256, 0, stream>>>(
          src + base * F, src + base * F, F, WB1, bcat, UV, CHUNK_ROWS, NN, F, Fpad);
      edge_stage2_m<<<CHUNK_ROWS / 16, 256, 0, stream>>>(
          UV, idx + base * 4, WB2, b2, dst + base * 192, H1, KpadW2);
    }
  };

  // a = edge(x) -> A ; b = edge(a) -> Bb      [fp32: feed KNN 2,3]
  edge_layer_f32(x,  4,   96,  P[1], P[2], P[3], P[4], A);
  edge_layer_f32(A,  192, 252, P[5], P[6], P[7], P[8], Bb);

  // h1 = x@Wx + nn1b, then += [a,b] @ nn1w[4:388]   [fp16x3]
  nn1_init<<<BN / 64, 256, 0, stream>>>(x, P[17], P[18], h1);
  {
    prep_wT<<<(252 * 384 + 255) / 256, 256, 0, stream>>>(P[17] + 4 * 252, 384, 252, 384, WB1);
    dim3 g(2, BN / 128);
    gemm3h<false, true, false><<<g, 256, 0, stream>>>(A, Bb, 192, WB1, nullptr, h1, BN, 252, 384, 384);
  }

  // c = edge(b) -> A   [fp32: feeds KNN 4] ; d = edge(c) -> Bb [fp16x3]
  edge_layer_f32(Bb, 192, 252, P[9],  P[10], P[11], P[12], A);
  edge_layer_f16(A,  192, 252, P[13], P[14], P[15], P[16], Bb);

  // h1 += [c,d] @ nn1w[388:772]   [fp16x3]
  {
    prep_wT<<<(252 * 384 + 255) / 256, 256, 0, stream>>>(P[17] + (size_t)388 * 252, 384, 252, 384, WB1);
    dim3 g(2, BN / 128);
    gemm3h<false, true, false><<<g, 256, 0, stream>>>(A, Bb, 192, WB1, nullptr, h1, BN, 252, 384, 384);
  }

  // nn2: h2 = leaky(h1) @ nn2w + nn2b -> A   [fp16x3]
  {
    prep_wT<<<(192 * 256 + 255) / 256, 256, 0, stream>>>(P[19], 252, 192, 256, WB2);
    dim3 g(2, BN / 128);
    gemm3h<true, false, true><<<g, 256, 0, stream>>>(h1, h1, 252, WB2, P[20], A, BN, 192, 252, 256);
  }

  pool_kernel<<<B_, 192, 0, stream>>>(A, pooled);
  head_kernel<<<B_, 128, 0, stream>>>(pooled, P[21], P[22], P[23], P[24], (float*)d_out);
}

// Round 8
// 2033.382 us; speedup vs baseline: 1.6354x; 1.0814x over previous
//
#include <hip/hip_runtime.h>
#include <cstdint>
#include <cstddef>

#define LK(x) ((x) > 0.f ? (x) : 0.01f * (x))

typedef _Float16 f16x8 __attribute__((ext_vector_type(8)));
typedef _Float16 f16x4 __attribute__((ext_vector_type(4)));
typedef float f32x4 __attribute__((ext_vector_type(4)));

constexpr int B_ = 256;
constexpr int N_ = 256;
constexpr int BN = B_ * N_;
constexpr int CHUNK_B = 64;                 // batches per UV chunk
constexpr int CHUNK_ROWS = CHUNK_B * N_;    // 16384 rows

// fp16 2-way split (for fp16x3 path)
__device__ inline void dec2(float v, _Float16& h, _Float16& l) {
  _Float16 hh = (_Float16)v;
  h = hh;
  l = (_Float16)(v - (float)hh);
}

// ---------------- KNN: one block per batch, one thread per point ----------------
__global__ void knn_kernel(const float* __restrict__ feat, int F, int* __restrict__ idxout) {
  __shared__ float px[N_], py[N_], pz[N_];
  int b = blockIdx.x, t = threadIdx.x;
  const float* row = feat + ((size_t)b * N_ + t) * F;
  px[t] = row[0]; py[t] = row[1]; pz[t] = row[2];
  __syncthreads();
  float x = px[t], y = py[t], z = pz[t];
  float bd0 = INFINITY, bd1 = INFINITY, bd2 = INFINITY, bd3 = INFINITY;
  int bi0 = 0, bi1 = 0, bi2 = 0, bi3 = 0;
  for (int j = 0; j < N_; ++j) {
    #pragma clang fp contract(off)
    float dx = x - px[j], dy = y - py[j], dz = z - pz[j];
    float d = (dx * dx + dy * dy) + dz * dz;
    if (j == t) continue;
    if (d < bd3) {
      if (d < bd2) {
        bd3 = bd2; bi3 = bi2;
        if (d < bd1) {
          bd2 = bd1; bi2 = bi1;
          if (d < bd0) { bd1 = bd0; bi1 = bi0; bd0 = d; bi0 = j; }
          else         { bd1 = d; bi1 = j; }
        } else         { bd2 = d; bi2 = j; }
      } else           { bd3 = d; bi3 = j; }
    }
  }
  int* o = idxout + ((size_t)b * N_ + t) * 4;
  o[0] = bi0; o[1] = bi1; o[2] = bi2; o[3] = bi3;
}

// ============================ fp32 path (bit-exact chain) ============================

// wcat = [w1_top - w1_bot | w1_bot] (F x 2H1), bcat = [b1 | 0]
__global__ void prep_uvw(const float* __restrict__ w1, const float* __restrict__ b1,
                         int F, int H1, float* __restrict__ wcat, float* __restrict__ bcat) {
  int t = blockIdx.x * 256 + threadIdx.x;
  int FH = F * H1;
  if (t < FH) {
    int k = t / H1, c = t - k * H1;
    float top = w1[(size_t)k * H1 + c];
    float bot = w1[(size_t)(F + k) * H1 + c];
    wcat[(size_t)k * 2 * H1 + c]      = top - bot;
    wcat[(size_t)k * 2 * H1 + H1 + c] = bot;
  }
  if (t < H1) { bcat[t] = b1[t]; bcat[H1 + t] = 0.f; }
}

// fp32 GEMM: 128x64 tile, BK=16, 256 thr, 8x4 micro (R3 verbatim)
template<bool ACT_A, bool ACCUM, bool HAS_BIAS>
__global__ __launch_bounds__(256) void gemm_f32(
    const float* __restrict__ A, const float* __restrict__ W,
    const float* __restrict__ bias, float* __restrict__ C,
    int M, int N, int K) {
  __shared__ float sA[16][132];
  __shared__ float sW[16][68];
  int tid = threadIdx.x;
  int m0 = blockIdx.y * 128;
  int n0 = blockIdx.x * 64;
  int kkA = tid & 15, mA = tid >> 4;
  int nW = tid & 63, kW = tid >> 6;
  int ty = tid >> 4, tx = tid & 15;
  float acc[8][4] = {};
  for (int k0 = 0; k0 < K; k0 += 16) {
    int kg = k0 + kkA;
    #pragma unroll
    for (int i = 0; i < 8; ++i) {
      int m = mA + i * 16;
      float v = 0.f;
      if (kg < K) {
        v = A[(size_t)(m0 + m) * K + kg];
        if (ACT_A) v = LK(v);
      }
      sA[kkA][m] = v;
    }
    #pragma unroll
    for (int q = 0; q < 4; ++q) {
      int kk = kW + q * 4;
      int kgw = k0 + kk, n = n0 + nW;
      float v = 0.f;
      if (kgw < K && n < N) v = W[(size_t)kgw * N + n];
      sW[kk][nW] = v;
    }
    __syncthreads();
    #pragma unroll
    for (int kk = 0; kk < 16; ++kk) {
      float4 a0 = *(const float4*)&sA[kk][ty * 8];
      float4 a1 = *(const float4*)&sA[kk][ty * 8 + 4];
      float4 w  = *(const float4*)&sW[kk][tx * 4];
      float av[8] = {a0.x, a0.y, a0.z, a0.w, a1.x, a1.y, a1.z, a1.w};
      float wv[4] = {w.x, w.y, w.z, w.w};
      #pragma unroll
      for (int i = 0; i < 8; ++i)
        #pragma unroll
        for (int j = 0; j < 4; ++j)
          acc[i][j] += av[i] * wv[j];
    }
    __syncthreads();
  }
  int n = n0 + tx * 4;
  float bv[4] = {0.f, 0.f, 0.f, 0.f};
  if (HAS_BIAS) {
    #pragma unroll
    for (int j = 0; j < 4; ++j) if (n + j < N) bv[j] = bias[n + j];
  }
  #pragma unroll
  for (int i = 0; i < 8; ++i) {
    size_t m = (size_t)(m0 + ty * 8 + i);
    if (n + 3 < N) {
      float4 o;
      o.x = acc[i][0] + bv[0]; o.y = acc[i][1] + bv[1];
      o.z = acc[i][2] + bv[2]; o.w = acc[i][3] + bv[3];
      float4* cp = (float4*)(C + m * N + n);
      if (ACCUM) { float4 c = *cp; o.x += c.x; o.y += c.y; o.z += c.z; o.w += c.w; }
      *cp = o;
    } else {
      #pragma unroll
      for (int j = 0; j < 4; ++j) {
        if (n + j < N) {
          float v = acc[i][j] + bv[j];
          size_t off = m * N + n + j;
          if (ACCUM) v += C[off];
          C[off] = v;
        }
      }
    }
  }
}

// fp32 fused edge stage 2, K-tiled (R3 verbatim) — layers 1,2
__global__ __launch_bounds__(256) void edge_stage2(
    const float* __restrict__ UV, const int* __restrict__ idx,
    const float* __restrict__ w2, const float* __restrict__ b2,
    float* __restrict__ out, int H1) {
  __shared__ float sH[16][68];
  __shared__ float sW[16][196];
  __shared__ int sJ[64];
  int tid = threadIdx.x;
  int g0 = blockIdx.x * 16;
  int bbase = (g0 >> 8) << 8;
  if (tid < 64) sJ[tid] = bbase + idx[(size_t)g0 * 4 + tid];
  int W2 = H1 * 2;
  int r = tid >> 2, seg = tid & 3;
  int gp_r = g0 + (r >> 2);
  int ty = tid >> 4, tx = tid & 15;
  int gp = g0 + ty;
  float acc[4][12] = {};
  int nKt = (H1 + 15) >> 4;
  for (int kt = 0; kt < nKt; ++kt) {
    int k0 = kt << 4;
    __syncthreads();
    {
      int c = k0 + (seg << 2);
      const float* up = UV + (size_t)gp_r * W2 + c;
      const float* vp = UV + (size_t)sJ[r] * W2 + H1 + c;
      float u[4], v[4];
      if (c + 3 < H1) {
        float4 uu = *(const float4*)up; float4 vv = *(const float4*)vp;
        u[0] = uu.x; u[1] = uu.y; u[2] = uu.z; u[3] = uu.w;
        v[0] = vv.x; v[1] = vv.y; v[2] = vv.z; v[3] = vv.w;
      } else {
        #pragma unroll
        for (int j = 0; j < 4; ++j) {
          u[j] = (c + j < H1) ? up[j] : 0.f;
          v[j] = (c + j < H1) ? vp[j] : 0.f;
        }
      }
      #pragma unroll
      for (int j = 0; j < 4; ++j) {
        float t = u[j] + v[j];
        sH[(seg << 2) + j][r] = (c + j < H1) ? LK(t) : 0.f;
      }
    }
    #pragma unroll
    for (int p = 0; p < 3; ++p) {
      int q = tid + (p << 8);
      int kk = q / 48;
      int c4 = q - kk * 48;
      int k = k0 + kk;
      float4 wv = {0.f, 0.f, 0.f, 0.f};
      if (k < H1) wv = *(const float4*)(w2 + (size_t)k * 192 + (c4 << 2));
      *(float4*)&sW[kk][c4 << 2] = wv;
    }
    __syncthreads();
    #pragma unroll
    for (int kk = 0; kk < 16; ++kk) {
      float4 a = *(const float4*)&sH[kk][ty << 2];
      float av[4] = {a.x, a.y, a.z, a.w};
      #pragma unroll
      for (int ct = 0; ct < 3; ++ct) {
        float4 w = *(const float4*)&sW[kk][ct * 64 + (tx << 2)];
        float wv[4] = {w.x, w.y, w.z, w.w};
        #pragma unroll
        for (int i = 0; i < 4; ++i)
          #pragma unroll
          for (int j = 0; j < 4; ++j)
            acc[i][ct * 4 + j] += av[i] * wv[j];
      }
    }
  }
  #pragma unroll
  for (int ct = 0; ct < 3; ++ct) {
    float o[4];
    #pragma unroll
    for (int j = 0; j < 4; ++j) {
      int col = ct * 64 + (tx << 2) + j;
      float bvv = b2[col];
      float s = 0.f;
      #pragma unroll
      for (int i = 0; i < 4; ++i) {
        float t = acc[i][ct * 4 + j] + bvv;
        s += LK(t);
      }
      o[j] = s;
    }
    float4 ov = {o[0], o[1], o[2], o[3]};
    *(float4*)(out + (size_t)gp * 192 + ct * 64 + (tx << 2)) = ov;
  }
}

// exact fp32 replica of stage2 for cols 0..2 ONLY (the KNN-feeding columns).
// 4 threads per point (one per edge); k-ascending fmaf chain identical to edge_stage2;
// 4-edge sum done in e-order via shuffles. Overwrites out[., 0..2].
__global__ __launch_bounds__(256) void edge_exact3(
    const float* __restrict__ UV, const int* __restrict__ idx,
    const float* __restrict__ w2, const float* __restrict__ b2,
    float* __restrict__ out, int H1) {
  __shared__ float sw[252 * 4];
  int tid = threadIdx.x;
  for (int k = tid; k < H1; k += 256) {
    sw[k * 4 + 0] = w2[(size_t)k * 192 + 0];
    sw[k * 4 + 1] = w2[(size_t)k * 192 + 1];
    sw[k * 4 + 2] = w2[(size_t)k * 192 + 2];
    sw[k * 4 + 3] = 0.f;
  }
  __syncthreads();
  int p = blockIdx.x * 64 + (tid >> 2);   // chunk-local point
  int e = tid & 3;
  int bbase = (p >> 8) << 8;
  int j = bbase + idx[(size_t)p * 4 + e];
  int W2 = 2 * H1;
  const float* up = UV + (size_t)p * W2;
  const float* vp = UV + (size_t)j * W2 + H1;
  float a0 = 0.f, a1 = 0.f, a2 = 0.f;
  int k = 0;
  for (; k + 3 < H1; k += 4) {
    float4 u = *(const float4*)(up + k);
    float4 v = *(const float4*)(vp + k);
    float h0 = LK(u.x + v.x), h1 = LK(u.y + v.y);
    float h2 = LK(u.z + v.z), h3 = LK(u.w + v.w);
    float4 w0 = *(const float4*)&sw[(k + 0) * 4];
    float4 w1 = *(const float4*)&sw[(k + 1) * 4];
    float4 w2v = *(const float4*)&sw[(k + 2) * 4];
    float4 w3 = *(const float4*)&sw[(k + 3) * 4];
    a0 = __builtin_fmaf(h0, w0.x, a0); a1 = __builtin_fmaf(h0, w0.y, a1); a2 = __builtin_fmaf(h0, w0.z, a2);
    a0 = __builtin_fmaf(h1, w1.x, a0); a1 = __builtin_fmaf(h1, w1.y, a1); a2 = __builtin_fmaf(h1, w1.z, a2);
    a0 = __builtin_fmaf(h2, w2v.x, a0); a1 = __builtin_fmaf(h2, w2v.y, a1); a2 = __builtin_fmaf(h2, w2v.z, a2);
    a0 = __builtin_fmaf(h3, w3.x, a0); a1 = __builtin_fmaf(h3, w3.y, a1); a2 = __builtin_fmaf(h3, w3.z, a2);
  }
  for (; k < H1; ++k) {
    float h = LK(up[k] + vp[k]);
    a0 = __builtin_fmaf(h, sw[k * 4 + 0], a0);
    a1 = __builtin_fmaf(h, sw[k * 4 + 1], a1);
    a2 = __builtin_fmaf(h, sw[k * 4 + 2], a2);
  }
  float acc3[3] = {a0, a1, a2};
  #pragma unroll
  for (int c = 0; c < 3; ++c) {
    float t = acc3[c] + b2[c];
    float pc = LK(t);
    float q1 = __shfl_down(pc, 1);
    float q2 = __shfl_down(pc, 2);
    float q3 = __shfl_down(pc, 3);
    if (e == 0) {
      float s = ((pc + q1) + q2) + q3;   // e-ascending order, matches edge_stage2 epilogue
      out[(size_t)p * 192 + c] = s;
    }
  }
}

// ====================== fp16x3 MFMA path (noise-tolerant GEMMs) ======================

// Wp[n][k-octets]: [8 hi | 8 lo]; [wdiff | wbot] transposed. bcat = [b1|0]
__global__ void prep_wcatT(const float* __restrict__ w1, const float* __restrict__ b1,
                           int F, int H1, int Fpad, _Float16* __restrict__ Wp,
                           float* __restrict__ bcat) {
  int t = blockIdx.x * 256 + threadIdx.x;
  int NN = 2 * H1;
  if (t < NN * Fpad) {
    int n = t / Fpad, k = t - n * Fpad;
    float v = 0.f;
    if (k < F) {
      if (n < H1) v = w1[(size_t)k * H1 + n] - w1[(size_t)(F + k) * H1 + n];
      else        v = w1[(size_t)(F + k) * H1 + (n - H1)];
    }
    _Float16 h, l; dec2(v, h, l);
    size_t base = (size_t)n * 2 * Fpad + (size_t)(k >> 3) * 16 + (k & 7);
    Wp[base] = h; Wp[base + 8] = l;
  }
  if (t < NN) bcat[t] = (t < H1) ? b1[t] : 0.f;
}

__global__ void prep_wT(const float* __restrict__ W, int K, int N, int Kpad,
                        _Float16* __restrict__ Wp) {
  int t = blockIdx.x * 256 + threadIdx.x;
  if (t >= N * Kpad) return;
  int n = t / Kpad, k = t - n * Kpad;
  float v = (k < K) ? W[(size_t)k * N + n] : 0.f;
  _Float16 h, l; dec2(v, h, l);
  size_t base = (size_t)n * 2 * Kpad + (size_t)(k >> 3) * 16 + (k & 7);
  Wp[base] = h; Wp[base + 8] = l;
}

// fp16x3 MFMA GEMM. Block 128x128, 4 waves (2x2), K-step 32.
// XB: epilogue adds x(Mx4) @ Wx(4xN) inline (nn1 first pass), plain store.
template<bool ACT_A, bool ACCUM, bool HAS_BIAS, bool XB>
__global__ __launch_bounds__(256) void gemm3h(
    const float* __restrict__ A0, const float* __restrict__ A1, int w0,
    const _Float16* __restrict__ Wp, const float* __restrict__ bias,
    const float* __restrict__ X, const float* __restrict__ Wx,
    float* __restrict__ C, int M, int N, int K, int Kpad) {
  __shared__ _Float16 sA[128 * 72];
  __shared__ _Float16 sB[128 * 72];
  int tid = threadIdx.x;
  int m0 = blockIdx.y * 128, n0 = blockIdx.x * 128;
  int lane = tid & 63, wid = tid >> 6;
  int wy = wid >> 1, wx = wid & 1;
  int lm = lane & 15, lq = lane >> 4;
  int rA = tid >> 1, qA = (tid & 1) * 4;
  f32x4 acc[4][4];
  #pragma unroll
  for (int i = 0; i < 4; ++i)
    #pragma unroll
    for (int j = 0; j < 4; ++j) acc[i][j] = 0.f;

  for (int k0 = 0; k0 < Kpad; k0 += 32) {
    __syncthreads();
    {
      const float* Ap; int kb, wA;
      if (k0 < w0) { Ap = A0; kb = k0;      wA = w0; }
      else         { Ap = A1; kb = k0 - w0; wA = K - w0; }
      const float* arow = Ap + (size_t)(m0 + rA) * wA;
      #pragma unroll
      for (int qi = 0; qi < 4; ++qi) {
        int q = qA + qi;
        int kl = kb + q * 4;
        float4 v = {0.f, 0.f, 0.f, 0.f};
        if (kl + 3 < wA) v = *(const float4*)(arow + kl);
        else {
          if (kl + 0 < wA) v.x = arow[kl + 0];
          if (kl + 1 < wA) v.y = arow[kl + 1];
          if (kl + 2 < wA) v.z = arow[kl + 2];
        }
        if (ACT_A) { v.x = LK(v.x); v.y = LK(v.y); v.z = LK(v.z); v.w = LK(v.w); }
        _Float16 h0,h1,h2,h3,l0,l1,l2,l3;
        dec2(v.x,h0,l0); dec2(v.y,h1,l1); dec2(v.z,h2,l2); dec2(v.w,h3,l3);
        int off = rA * 72 + (q >> 1) * 16 + (q & 1) * 4;
        f16x4 th; th[0]=h0; th[1]=h1; th[2]=h2; th[3]=h3;
        f16x4 tl; tl[0]=l0; tl[1]=l1; tl[2]=l2; tl[3]=l3;
        *(f16x4*)&sA[off]     = th;
        *(f16x4*)&sA[off + 8] = tl;
      }
    }
    {
      int n = n0 + rA;
      const _Float16* src = Wp + (size_t)n * 2 * Kpad + (size_t)k0 * 2;
      #pragma unroll
      for (int ui = 0; ui < 4; ++ui) {
        int u = (tid & 1) * 4 + ui;
        float4 v = {0.f, 0.f, 0.f, 0.f};
        if (n < N) v = *(const float4*)(src + u * 8);
        *(float4*)&sB[rA * 72 + u * 8] = v;
      }
    }
    __syncthreads();
    f16x8 af[4][2], bf[4][2];
    #pragma unroll
    for (int mt = 0; mt < 4; ++mt) {
      int row = wy * 64 + mt * 16 + lm;
      af[mt][0] = *(const f16x8*)&sA[row * 72 + lq * 16];
      af[mt][1] = *(const f16x8*)&sA[row * 72 + lq * 16 + 8];
    }
    #pragma unroll
    for (int nt = 0; nt < 4; ++nt) {
      int row = wx * 64 + nt * 16 + lm;
      bf[nt][0] = *(const f16x8*)&sB[row * 72 + lq * 16];
      bf[nt][1] = *(const f16x8*)&sB[row * 72 + lq * 16 + 8];
    }
    #pragma unroll
    for (int mt = 0; mt < 4; ++mt)
      #pragma unroll
      for (int nt = 0; nt < 4; ++nt) {
        acc[mt][nt] = __builtin_amdgcn_mfma_f32_16x16x32_f16(af[mt][0], bf[nt][0], acc[mt][nt], 0, 0, 0);
        acc[mt][nt] = __builtin_amdgcn_mfma_f32_16x16x32_f16(af[mt][0], bf[nt][1], acc[mt][nt], 0, 0, 0);
        acc[mt][nt] = __builtin_amdgcn_mfma_f32_16x16x32_f16(af[mt][1], bf[nt][0], acc[mt][nt], 0, 0, 0);
      }
  }
  if (XB) {
    #pragma unroll
    for (int mt = 0; mt < 4; ++mt) {
      #pragma unroll
      for (int r = 0; r < 4; ++r) {
        size_t m = (size_t)m0 + wy * 64 + mt * 16 + lq * 4 + r;
        float4 xv = *(const float4*)(X + m * 4);
        #pragma unroll
        for (int nt = 0; nt < 4; ++nt) {
          int n = n0 + wx * 64 + nt * 16 + lm;
          if (n >= N) continue;
          float v = acc[mt][nt][r] + bias[n]
                  + (xv.x * Wx[n] + xv.y * Wx[N + n] + xv.z * Wx[2 * N + n] + xv.w * Wx[3 * N + n]);
          C[m * N + n] = v;
        }
      }
    }
    return;
  }
  #pragma unroll
  for (int mt = 0; mt < 4; ++mt) {
    #pragma unroll
    for (int nt = 0; nt < 4; ++nt) {
      int n = n0 + wx * 64 + nt * 16 + lm;
      if (n >= N) continue;
      float bv = HAS_BIAS ? bias[n] : 0.f;
      #pragma unroll
      for (int r = 0; r < 4; ++r) {
        size_t m = (size_t)m0 + wy * 64 + mt * 16 + lq * 4 + r;
        float v = acc[mt][nt][r] + bv;
        size_t off = m * N + n;
        if (ACCUM) v += C[off];
        C[off] = v;
      }
    }
  }
}

// fp16x3 fused edge stage 2 (layers 3 cols + layer 4)
__global__ __launch_bounds__(256) void edge_stage2_m(
    const float* __restrict__ UV, const int* __restrict__ idx,
    const _Float16* __restrict__ Wp, const float* __restrict__ b2,
    float* __restrict__ out, int H1, int Kpad) {
  __shared__ _Float16 sH[64 * 72];
  __shared__ _Float16 sW[192 * 72];
  __shared__ int sJ[64];
  int tid = threadIdx.x;
  int g0 = blockIdx.x * 16;
  int bbase = (g0 >> 8) << 8;
  if (tid < 64) sJ[tid] = bbase + idx[(size_t)g0 * 4 + tid];
  int W2 = 2 * H1;
  int lane = tid & 63, w = tid >> 6;
  int lm = lane & 15, lq = lane >> 4;
  int rS = tid >> 2, qS = tid & 3;
  f32x4 acc[4][3];
  #pragma unroll
  for (int i = 0; i < 4; ++i)
    #pragma unroll
    for (int j = 0; j < 3; ++j) acc[i][j] = 0.f;

  for (int k0 = 0; k0 < Kpad; k0 += 32) {
    __syncthreads();
    {
      int gp_r = g0 + (rS >> 2);
      int jr = sJ[rS];
      const float* up = UV + (size_t)gp_r * W2;
      const float* vp = UV + (size_t)jr * W2 + H1;
      #pragma unroll
      for (int hf = 0; hf < 2; ++hf) {
        int k = k0 + qS * 8 + hf * 4;
        float4 u = {0.f,0.f,0.f,0.f}, v = {0.f,0.f,0.f,0.f};
        if (k + 3 < H1) { u = *(const float4*)(up + k); v = *(const float4*)(vp + k); }
        else {
          if (k + 0 < H1) { u.x = up[k+0]; v.x = vp[k+0]; }
          if (k + 1 < H1) { u.y = up[k+1]; v.y = vp[k+1]; }
          if (k + 2 < H1) { u.z = up[k+2]; v.z = vp[k+2]; }
        }
        float e0 = LK(u.x + v.x), e1 = LK(u.y + v.y), e2 = LK(u.z + v.z), e3 = LK(u.w + v.w);
        _Float16 h0,h1,h2,h3,l0,l1,l2,l3;
        dec2(e0,h0,l0); dec2(e1,h1,l1); dec2(e2,h2,l2); dec2(e3,h3,l3);
        int off = rS * 72 + qS * 16 + hf * 4;
        f16x4 th; th[0]=h0; th[1]=h1; th[2]=h2; th[3]=h3;
        f16x4 tl; tl[0]=l0; tl[1]=l1; tl[2]=l2; tl[3]=l3;
        *(f16x4*)&sH[off]     = th;
        *(f16x4*)&sH[off + 8] = tl;
      }
    }
    {
      const _Float16* src = Wp + (size_t)k0 * 2;
      #pragma unroll
      for (int p = 0; p < 6; ++p) {
        int e = tid + p * 256;
        int n = e >> 3, u = e & 7;
        *(float4*)&sW[n * 72 + u * 8] =
            *(const float4*)(src + (size_t)n * 2 * Kpad + u * 8);
      }
    }
    __syncthreads();
    f16x8 af[4][2], bf[3][2];
    #pragma unroll
    for (int mt = 0; mt < 4; ++mt) {
      int row = mt * 16 + lm;
      af[mt][0] = *(const f16x8*)&sH[row * 72 + lq * 16];
      af[mt][1] = *(const f16x8*)&sH[row * 72 + lq * 16 + 8];
    }
    #pragma unroll
    for (int t3 = 0; t3 < 3; ++t3) {
      int row = (w * 3 + t3) * 16 + lm;
      bf[t3][0] = *(const f16x8*)&sW[row * 72 + lq * 16];
      bf[t3][1] = *(const f16x8*)&sW[row * 72 + lq * 16 + 8];
    }
    #pragma unroll
    for (int mt = 0; mt < 4; ++mt)
      #pragma unroll
      for (int t3 = 0; t3 < 3; ++t3) {
        acc[mt][t3] = __builtin_amdgcn_mfma_f32_16x16x32_f16(af[mt][0], bf[t3][0], acc[mt][t3], 0, 0, 0);
        acc[mt][t3] = __builtin_amdgcn_mfma_f32_16x16x32_f16(af[mt][0], bf[t3][1], acc[mt][t3], 0, 0, 0);
        acc[mt][t3] = __builtin_amdgcn_mfma_f32_16x16x32_f16(af[mt][1], bf[t3][0], acc[mt][t3], 0, 0, 0);
      }
  }
  #pragma unroll
  for (int mt = 0; mt < 4; ++mt) {
    int gp = g0 + mt * 4 + lq;
    #pragma unroll
    for (int t3 = 0; t3 < 3; ++t3) {
      int col = (w * 3 + t3) * 16 + lm;
      float bv = b2[col];
      float s = 0.f;
      #pragma unroll
      for (int r = 0; r < 4; ++r) s += LK(acc[mt][t3][r] + bv);
      out[(size_t)gp * 192 + col] = s;
    }
  }
}

// ---------------- pooling ----------------
__global__ void pool_kernel(const float* __restrict__ h, float* __restrict__ pooled) {
  int b = blockIdx.x, ch = threadIdx.x;  // 192 threads
  const float* p = h + (size_t)b * N_ * 192 + ch;
  float mx = -INFINITY, mn = INFINITY, sm = 0.f;
  for (int n = 0; n < N_; ++n) {
    float v = p[(size_t)n * 192];
    mx = fmaxf(mx, v); mn = fminf(mn, v); sm += v;
  }
  float* o = pooled + (size_t)b * 768;
  o[ch]       = LK(mx);
  o[192 + ch] = LK(mn);
  o[384 + ch] = LK(sm);
  o[576 + ch] = LK(sm * (1.f / 256.f));
}

// ---------------- head ----------------
__global__ void head_kernel(const float* __restrict__ pooled,
                            const float* __restrict__ w3, const float* __restrict__ b3,
                            const float* __restrict__ w4, const float* __restrict__ b4,
                            float* __restrict__ out) {
  __shared__ float sp[768];
  __shared__ float st[96];
  int b = blockIdx.x, t = threadIdx.x;   // 128 threads
  for (int c = t; c < 768; c += 128) sp[c] = pooled[(size_t)b * 768 + c];
  __syncthreads();
  if (t < 96) {
    float s = b3[t];
    for (int r = 0; r < 768; ++r) s += sp[r] * w3[(size_t)r * 96 + t];
    s = LK(s);
    st[t] = s * w4[t];
  }
  __syncthreads();
  if (t == 0) {
    float s = b4[0];
    for (int i = 0; i < 96; ++i) s += st[i];
    out[b] = s;
  }
}

extern "C" void kernel_launch(void* const* d_in, const int* in_sizes, int n_in,
                              void* d_out, int out_size, void* d_ws, size_t ws_size,
                              hipStream_t stream) {
  (void)in_sizes; (void)n_in; (void)out_size; (void)ws_size;
  const float* x = (const float*)d_in[0];
  const float* P[25];
  for (int i = 0; i < 25; ++i) P[i] = (const float*)d_in[i];

  // ---- workspace layout (peak ~203.7 MB) ----
  char* ws = (char*)d_ws;
  int*   idx    = (int*)  (ws + 0);            //  1,048,576
  float* A      = (float*)(ws + 1048576);      // 50,331,648  (a, c, then h2)
  float* Bb     = (float*)(ws + 51380224);     // 50,331,648  (b, then d)
  float* h1     = (float*)(ws + 101711872);    // 66,060,288
  float* UV     = (float*)(ws + 167772160);    // 33,030,144  (chunk [U|V])
  float* pooled = (float*)(ws + 200802304);    //    786,432
  char*  Wsl1   =         (ws + 201588736);    //  1,048,576  (fp32 wcat OR fp16 WB1)
  char*  Wsl2   =         (ws + 202637312);    //  1,048,576
  float* bcat   = (float*)(ws + 203685888);    //      4,096

  float*    wcat = (float*)   Wsl1;
  _Float16* WB1  = (_Float16*)Wsl1;
  _Float16* WB2  = (_Float16*)Wsl2;

  // ---- fp32 edge layer (layers 1,2: fully bit-exact) ----
  auto edge_layer_f32 = [&](const float* src, int F, int H1,
                            const float* w1, const float* b1,
                            const float* w2, const float* b2, float* dst) {
    knn_kernel<<<B_, N_, 0, stream>>>(src, F, idx);
    prep_uvw<<<(F * H1 + 255) / 256, 256, 0, stream>>>(w1, b1, F, H1, wcat, bcat);
    int W2 = 2 * H1;
    dim3 gUV((W2 + 63) / 64, CHUNK_ROWS / 128);
    for (int cb = 0; cb < B_; cb += CHUNK_B) {
      size_t base = (size_t)cb * N_;
      gemm_f32<false, false, true><<<gUV, 256, 0, stream>>>(src + base * F, wcat, bcat, UV, CHUNK_ROWS, W2, F);
      edge_stage2<<<CHUNK_ROWS / 16, 256, 0, stream>>>(UV, idx + base * 4, w2, b2, dst + base * 192, H1);
    }
  };

  // ---- fp16x3 edge layer (layer 4: output feeds no KNN) ----
  auto edge_layer_f16 = [&](const float* src, int F, int H1,
                            const float* w1, const float* b1,
                            const float* w2, const float* b2, float* dst) {
    int Fpad = (F + 31) & ~31;
    int KpadW2 = (H1 + 31) & ~31;
    int NN = 2 * H1;
    knn_kernel<<<B_, N_, 0, stream>>>(src, F, idx);
    prep_wcatT<<<(NN * Fpad + 255) / 256, 256, 0, stream>>>(w1, b1, F, H1, Fpad, WB1, bcat);
    prep_wT<<<(192 * KpadW2 + 255) / 256, 256, 0, stream>>>(w2, H1, 192, KpadW2, WB2);
    dim3 gUV((NN + 127) / 128, CHUNK_ROWS / 128);
    for (int cb = 0; cb < B_; cb += CHUNK_B) {
      size_t base = (size_t)cb * N_;
      gemm3h<false, false, true, false><<<gUV, 256, 0, stream>>>(
          src + base * F, src + base * F, F, WB1, bcat, nullptr, nullptr, UV, CHUNK_ROWS, NN, F, Fpad);
      edge_stage2_m<<<CHUNK_ROWS / 16, 256, 0, stream>>>(
          UV, idx + base * 4, WB2, b2, dst + base * 192, H1, KpadW2);
    }
  };

  // a = edge(x) -> A ; b = edge(a) -> Bb      [fp32 exact: feed KNN 2,3 via full GEMMs]
  edge_layer_f32(x,  4,   96,  P[1], P[2], P[3], P[4], A);
  edge_layer_f32(A,  192, 252, P[5], P[6], P[7], P[8], Bb);

  // h1 = [x,a,b] @ nn1w[0:388] + nn1b   [fp16x3, x-part fused into epilogue]
  {
    prep_wT<<<(252 * 384 + 255) / 256, 256, 0, stream>>>(P[17] + 4 * 252, 384, 252, 384, WB1);
    dim3 g(2, BN / 128);
    gemm3h<false, false, true, true><<<g, 256, 0, stream>>>(
        A, Bb, 192, WB1, P[18], x, P[17], h1, BN, 252, 384, 384);
  }

  // c = edge(b) -> A   [hybrid: fp32 UV (exact) + fp16x3 stage2 + exact fp32 cols 0-2]
  {
    const float* src = Bb;
    const float* w1 = P[9]; const float* b1 = P[10];
    const float* w2 = P[11]; const float* b2 = P[12];
    float* dst = A;
    int F = 192, H1 = 252, W2 = 504, KpadW2 = 256;
    knn_kernel<<<B_, N_, 0, stream>>>(src, F, idx);
    prep_uvw<<<(F * H1 + 255) / 256, 256, 0, stream>>>(w1, b1, F, H1, wcat, bcat);
    prep_wT<<<(192 * KpadW2 + 255) / 256, 256, 0, stream>>>(w2, H1, 192, KpadW2, WB2);
    dim3 gUV((W2 + 63) / 64, CHUNK_ROWS / 128);
    for (int cb = 0; cb < B_; cb += CHUNK_B) {
      size_t base = (size_t)cb * N_;
      gemm_f32<false, false, true><<<gUV, 256, 0, stream>>>(src + base * F, wcat, bcat, UV, CHUNK_ROWS, W2, F);
      edge_stage2_m<<<CHUNK_ROWS / 16, 256, 0, stream>>>(UV, idx + base * 4, WB2, b2, dst + base * 192, H1, KpadW2);
      edge_exact3<<<CHUNK_ROWS / 64, 256, 0, stream>>>(UV, idx + base * 4, w2, b2, dst + base * 192, H1);
    }
  }

  // d = edge(c) -> Bb   [fp16x3]
  edge_layer_f16(A, 192, 252, P[13], P[14], P[15], P[16], Bb);

  // h1 += [c,d] @ nn1w[388:772]   [fp16x3]
  {
    prep_wT<<<(252 * 384 + 255) / 256, 256, 0, stream>>>(P[17] + (size_t)388 * 252, 384, 252, 384, WB1);
    dim3 g(2, BN / 128);
    gemm3h<false, true, false, false><<<g, 256, 0, stream>>>(
        A, Bb, 192, WB1, nullptr, nullptr, nullptr, h1, BN, 252, 384, 384);
  }

  // nn2: h2 = leaky(h1) @ nn2w + nn2b -> A   [fp16x3]
  {
    prep_wT<<<(192 * 256 + 255) / 256, 256, 0, stream>>>(P[19], 252, 192, 256, WB2);
    dim3 g(2, BN / 128);
    gemm3h<true, false, true, false><<<g, 256, 0, stream>>>(
        h1, h1, 252, WB2, P[20], nullptr, nullptr, A, BN, 192, 252, 256);
  }

  pool_kernel<<<B_, 192, 0, stream>>>(A, pooled);
  head_kernel<<<B_, 128, 0, stream>>>(pooled, P[21], P[22], P[23], P[24], (float*)d_out);
}